// Round 1
// baseline (441.153 us; speedup 1.0000x reference)
//
#include <hip/hip_runtime.h>

// Shapes fixed by the reference setup_inputs():
//   x: [B=8, F=512, T=16384] f32 ; out: [8, 16384] f32
#define TT 16384
#define BB 8
#define NB 8      // N_BANDS
#define FB 64     // F / N_BANDS

__device__ __forceinline__ float lgf(float g, float x) {
    // log1p(g*x) with g*x in [0,10): 1+g*x in [1,11) -> fast hw log is safe.
    return __logf(fmaf(g, x, 1.0f));
}

// ---------------- Kernel A: log-gamma + depthwise 5-tap diff + ReLU + freq-pool
// grid: (64 = b*8+c, 16 time tiles of 1024), block 256, 4 outputs/thread.
__global__ __launch_bounds__(256) void pool_kernel(
    const float* __restrict__ x,
    const float* __restrict__ log_gamma,
    const float* __restrict__ diff_w,   // [8,1,1,5] flat
    const float* __restrict__ diff_b,   // [8]
    float* __restrict__ pool)           // [8,8,16384]
{
    const int bc = blockIdx.x;                 // b*8 + c
    const int c  = bc & 7;
    const int t0 = blockIdx.y * 1024 + threadIdx.x * 4;
    const float* __restrict__ xb = x + (size_t)bc * FB * TT;  // (b*512 + c*64) rows

    const float g  = __expf(log_gamma[c]);
    const float w0 = diff_w[c * 5 + 0], w1 = diff_w[c * 5 + 1],
                w2 = diff_w[c * 5 + 2], w3 = diff_w[c * 5 + 3],
                w4 = diff_w[c * 5 + 4];
    const float bias = diff_b[c];

    const bool hasL = (t0 > 0);          // t0 is mult of 4, so t0-1,t0-2 both valid iff t0>0
    const bool has4 = (t0 + 4 < TT);
    const bool has5 = (t0 + 5 < TT);

    float a0 = 0.f, a1 = 0.f, a2 = 0.f, a3 = 0.f;
    for (int f = 0; f < FB; ++f) {
        const float* __restrict__ row = xb + (size_t)f * TT;
        const float4 v = *reinterpret_cast<const float4*>(row + t0);
        // x_log values at positions t0-2 .. t0+5 (zero outside [0,T): SAME padding on x_log)
        float l0 = 0.f, l1 = 0.f, l6 = 0.f, l7 = 0.f;
        if (hasL) { l0 = lgf(g, row[t0 - 2]); l1 = lgf(g, row[t0 - 1]); }
        if (has4) l6 = lgf(g, row[t0 + 4]);
        if (has5) l7 = lgf(g, row[t0 + 5]);
        const float l2 = lgf(g, v.x), l3 = lgf(g, v.y),
                    l4 = lgf(g, v.z), l5 = lgf(g, v.w);

        float d0 = fmaf(w0,l0, fmaf(w1,l1, fmaf(w2,l2, fmaf(w3,l3, fmaf(w4,l4, bias)))));
        float d1 = fmaf(w0,l1, fmaf(w1,l2, fmaf(w2,l3, fmaf(w3,l4, fmaf(w4,l5, bias)))));
        float d2 = fmaf(w0,l2, fmaf(w1,l3, fmaf(w2,l4, fmaf(w3,l5, fmaf(w4,l6, bias)))));
        float d3 = fmaf(w0,l3, fmaf(w1,l4, fmaf(w2,l5, fmaf(w3,l6, fmaf(w4,l7, bias)))));
        a0 += (d0 >= 0.f) ? d0 : 0.f;   // lrelu, A_LRELU = 0
        a1 += (d1 >= 0.f) ? d1 : 0.f;
        a2 += (d2 >= 0.f) ? d2 : 0.f;
        a3 += (d3 >= 0.f) ? d3 : 0.f;
    }
    *reinterpret_cast<float4*>(pool + (size_t)bc * TT + t0) = make_float4(a0, a1, a2, a3);
}

// ---------------- Kernel B: (pool - avg11 - avg_b) -> band mix -> gauss15 -> ReLU
// grid: 8 batches * 16 tiles of 1024, block 256. Writes unnormalized act + per-batch max.
__global__ __launch_bounds__(256) void smooth_kernel(
    const float* __restrict__ pool,     // [8,8,16384]
    const float* __restrict__ avg_w,    // [8,1,11] flat
    const float* __restrict__ avg_b,    // [8]
    const float* __restrict__ mix_w,    // [1,8] flat
    const float* __restrict__ gauss_w,  // [15]
    const float* __restrict__ gauss_b,  // [1]
    float* __restrict__ out,            // [8,16384] (unnormalized act)
    unsigned int* __restrict__ maxes)   // [8] f32-as-uint, pre-zeroed
{
    __shared__ float sp[NB][1024 + 24]; // pool tile, halo 12 each side (avg±5 then gauss±7)
    __shared__ float sm[1024 + 14];     // x_mix tile, halo 7 each side

    const int b  = blockIdx.x >> 4;
    const int t0 = (blockIdx.x & 15) * 1024;

    for (int i = threadIdx.x; i < 1024 + 24; i += 256) {
        const int t = t0 + i - 12;
        const bool in = ((unsigned)t < (unsigned)TT);
        #pragma unroll
        for (int c = 0; c < NB; ++c)
            sp[c][i] = in ? pool[((size_t)b * NB + c) * TT + t] : 0.f;
    }
    __syncthreads();

    // x_mix[t] = sum_c mix_w[c] * (pool_c[t] - sum_j avg_w[c,j]*pool_c[t+j-5] - avg_b[c])
    for (int i = threadIdx.x; i < 1024 + 14; i += 256) {
        const int t = t0 + i - 7;
        float v = 0.f;
        if ((unsigned)t < (unsigned)TT) {     // gauss pads x_mix (not extrapolated)
            #pragma unroll
            for (int c = 0; c < NB; ++c) {
                float av = 0.f;
                #pragma unroll
                for (int j = 0; j < 11; ++j)
                    av = fmaf(avg_w[c * 11 + j], sp[c][i + j], av);
                const float e = sp[c][i + 5] - av - avg_b[c];
                v = fmaf(mix_w[c], e, v);
            }
        }
        sm[i] = v;
    }
    __syncthreads();

    const float gb = gauss_b[0];
    float lmax = 0.f;
    for (int i = threadIdx.x; i < 1024; i += 256) {
        float gs = gb;
        #pragma unroll
        for (int k = 0; k < 15; ++k)
            gs = fmaf(gauss_w[k], sm[i + k], gs);
        const float a = (gs >= 0.f) ? gs : 0.f;   // lrelu, A_LRELU = 0
        out[(size_t)b * TT + t0 + i] = a;
        lmax = fmaxf(lmax, a);
    }
    #pragma unroll
    for (int off = 32; off > 0; off >>= 1)
        lmax = fmaxf(lmax, __shfl_down(lmax, off, 64));
    if ((threadIdx.x & 63) == 0)
        atomicMax(&maxes[b], __float_as_uint(lmax));   // act >= 0 so uint order == float order
}

// ---------------- Kernel C: divide by (max + eps), in place
__global__ __launch_bounds__(256) void norm_kernel(
    float* __restrict__ out, const unsigned int* __restrict__ maxes)
{
    const int i = blockIdx.x * 256 + threadIdx.x;   // grid sized exactly B*T/256
    const int b = i >> 14;                          // T = 16384
    const float m = __uint_as_float(maxes[b]);
    out[i] = out[i] / (m + 1e-8f);
}

extern "C" void kernel_launch(void* const* d_in, const int* in_sizes, int n_in,
                              void* d_out, int out_size, void* d_ws, size_t ws_size,
                              hipStream_t stream) {
    const float* x        = (const float*)d_in[0];
    const float* log_g    = (const float*)d_in[1];
    const float* diff_w   = (const float*)d_in[2];
    const float* diff_b   = (const float*)d_in[3];
    const float* avg_w    = (const float*)d_in[4];
    const float* avg_b    = (const float*)d_in[5];
    const float* mix_w    = (const float*)d_in[6];
    const float* gauss_w  = (const float*)d_in[7];
    const float* gauss_b  = (const float*)d_in[8];
    float* out = (float*)d_out;

    // workspace layout: pool [8*8*16384] f32 (4 MiB), then 8 uints for maxes
    float* pool = (float*)d_ws;
    unsigned int* maxes = (unsigned int*)((char*)d_ws + (size_t)BB * NB * TT * sizeof(float));

    pool_kernel<<<dim3(BB * NB, TT / 1024), 256, 0, stream>>>(x, log_g, diff_w, diff_b, pool);
    hipMemsetAsync(maxes, 0, BB * sizeof(unsigned int), stream);  // capture-safe async memset
    smooth_kernel<<<BB * (TT / 1024), 256, 0, stream>>>(pool, avg_w, avg_b, mix_w,
                                                        gauss_w, gauss_b, out, maxes);
    norm_kernel<<<(BB * TT) / 256, 256, 0, stream>>>(out, maxes);
}